// Round 13
// baseline (1110.728 us; speedup 1.0000x reference)
//
#include <hip/hip_runtime.h>
#include <cstdint>
#include <cstddef>

#define HDIM 2048
#define VOCAB 32000
#define BT 4096      // B*T tokens
#define NVB 125      // VOCAB / 256
#define BETA_F 0.1f
#define SCALE_X 16.0f
#define SCALE_W 64.0f
#define INV_SC (1.0f / (SCALE_X * SCALE_W))

typedef float f32x4 __attribute__((ext_vector_type(4)));
typedef long lx2 __attribute__((ext_vector_type(2)));

// ---------------------------------------------------------------- helpers
__device__ __forceinline__ void async_lds16(const void* g, void* l) {
  __builtin_amdgcn_global_load_lds(
      (__attribute__((address_space(1))) void*)g,
      (__attribute__((address_space(3))) void*)l,
      16, 0, 0);
}

#define BAR() __builtin_amdgcn_s_barrier()
#define SCHED0() __builtin_amdgcn_sched_barrier(0)
#define VMCNT(n) do { asm volatile("s_waitcnt vmcnt(" #n ")" ::: "memory"); \
                      __builtin_amdgcn_sched_barrier(0); } while (0)

// ---------------------------------------------------------------- cast fp32 -> fp8 e4m3 (16 elems/thread), scaled
__global__ void cast_fp8_kernel(const float* __restrict__ src,
                                uint4* __restrict__ dst, int n16, float scale) {
  int i = blockIdx.x * blockDim.x + threadIdx.x;
  int stride = gridDim.x * blockDim.x;
  for (; i < n16; i += stride) {
    const float4* s = (const float4*)src + (size_t)i * 4;
    uint4 o;
    {
      float4 a = s[0];
      int r = __builtin_amdgcn_cvt_pk_fp8_f32(a.x * scale, a.y * scale, 0, false);
      o.x = __builtin_amdgcn_cvt_pk_fp8_f32(a.z * scale, a.w * scale, r, true);
    }
    {
      float4 a = s[1];
      int r = __builtin_amdgcn_cvt_pk_fp8_f32(a.x * scale, a.y * scale, 0, false);
      o.y = __builtin_amdgcn_cvt_pk_fp8_f32(a.z * scale, a.w * scale, r, true);
    }
    {
      float4 a = s[2];
      int r = __builtin_amdgcn_cvt_pk_fp8_f32(a.x * scale, a.y * scale, 0, false);
      o.z = __builtin_amdgcn_cvt_pk_fp8_f32(a.z * scale, a.w * scale, r, true);
    }
    {
      float4 a = s[3];
      int r = __builtin_amdgcn_cvt_pk_fp8_f32(a.x * scale, a.y * scale, 0, false);
      o.w = __builtin_amdgcn_cvt_pk_fp8_f32(a.z * scale, a.w * scale, r, true);
    }
    dst[i] = o;
  }
}

// ---------------------------------------------------------------- 256x256 fp8 GEMM + LSE partials, 16 waves
// R11's verified 16-wave quadrant-pipelined schedule + T4 counted vmcnt:
// 4 LDS buffers (literal indices; rule #20), stage depth 3 tiles ahead,
// VMCNT(4)+BAR at each handoff -> 4 stage ops stay in flight across every
// barrier; vmcnt(0) only at the epilogue. R11/R12 drained vmcnt(0) at all
// 64 handoffs (m218: drain-0 ~ un-pipelined; counted = +38-73%).
//
// LDS half-tile: [row(128)][4 chunks x 16B], chunk c of a row's 64-B K-slab =
// [kk0-slot-c | kk1-slot-c] (K-permutation; cancels between A and B). One
// ds_read_b128 per row yields both kk fragments, conflict-free (R5/R9/R11: 0).
// Swizzle: physical ^= ((row>>3)&1)<<5; staging source pre-swizzled.
// Wave w stages rows (w>>3)*128 + (w&7)*16.. -> granule w*1024 per half-pair.
//
// WAR proofs: stage of buf (c+3)&3 during tile T is ordered by the barrier at
// the (T-1)->T handoff (its readers consumed data before that barrier);
// VMCNT(4) before BAR makes "tile T+1 landed" block-wide. Tail clamps restage
// real bytes into dead buffers (readers retired; checked tiles 29-31).
//
// NOTE 1024-thread block REQUIRES <=128 VGPR/wave. acc 64 + frags 32 + addr
// fits. Spill tripwire: WRITE_SIZE balloons (R4/R8). No VGPR cap beyond.
__global__ __launch_bounds__(1024) void gemm_lse256(
    const unsigned char* __restrict__ Xq,
    const unsigned char* __restrict__ Xrq,
    const unsigned char* __restrict__ Wq,
    const unsigned char* __restrict__ Wrq,
    float2* __restrict__ part) {
  __shared__ __align__(16) char lds[4][2][2][8192];  // [buf][A/B][half]

  const int tid = threadIdx.x;
  const int lane = tid & 63;
  const int w = tid >> 6;        // wave 0..15
  const int wm = w >> 2;         // 0..3 : M 64-row band
  const int wn = w & 3;          // 0..3 : N 64-col band
  const int which = blockIdx.y;  // 0 = policy, 1 = reference

  // XCD-aware bijective swizzle: 2000 blocks = 8 XCDs x 250, mb fastest within chunk.
  const int lin = blockIdx.x;
  const int nl = (lin & 7) * 250 + (lin >> 3);
  const int mb = nl & 15;        // 0..15
  const int nb = nl >> 4;        // 0..124

  const unsigned char* A = which ? Xrq : Xq;
  const unsigned char* B = which ? Wrq : Wq;
  float2* pp = part + (size_t)which * BT * NVB;

  // ---- staging addressing (source pre-swizzled to undo read-side XOR) ----
  const int lanep = lane ^ ((lane & 32) >> 4);
  const int srow = (w >> 3) * 128 + (w & 7) * 16 + (lanep >> 2);  // row in 256-row tile
  const int scol = (lanep & 3) * 16;                              // byte col in 64-B K-slab
  const unsigned char* Ag = A + (size_t)(mb * 256 + srow) * HDIM + scol;
  const unsigned char* Bg = B + (size_t)(nb * 256 + srow) * HDIM + scol;

#define STAGE_AB(buf, T) do {                                                 \
    int _t = (T) > 31 ? 31 : (T);                                             \
    async_lds16(Ag + (size_t)_t * 64, &lds[buf][0][0][0] + w * 1024);         \
    async_lds16(Bg + (size_t)_t * 64, &lds[buf][1][0][0] + w * 1024);         \
  } while (0)

  // ---- paired fragment read (swizzled b128 -> kk0 + kk1), R5/R9/R11-verified ----
  const int l15 = lane & 15;
  const int kbyte = (lane >> 4) * 16;
#define FRAGP(d0, d1, halfptr, row) do {                                      \
    int _r = (row);                                                           \
    int _L = _r * 64 + kbyte;                                                 \
    lx2 _v = *(const lx2*)((halfptr) + (_L ^ (((_r >> 3) & 1) << 5)));        \
    d0 = _v.x; d1 = _v.y;                                                     \
  } while (0)

  const char* Ah[4] = { &lds[0][0][wm >> 1][0], &lds[1][0][wm >> 1][0],
                        &lds[2][0][wm >> 1][0], &lds[3][0][wm >> 1][0] };
  const char* Bh[4] = { &lds[0][1][wn >> 1][0], &lds[1][1][wn >> 1][0],
                        &lds[2][1][wn >> 1][0], &lds[3][1][wn >> 1][0] };
  const int arow = (wm & 1) * 64 + l15;
  const int brow = (wn & 1) * 64 + l15;

  f32x4 acc[4][4] = {};
  long aLo[2][2], aHi[2][2], bLo[2][2], bHi[2][2];

#define RD_ALO(buf) do {                                                      \
    _Pragma("unroll") for (int mi = 0; mi < 2; ++mi)                          \
      FRAGP(aLo[mi][0], aLo[mi][1], Ah[buf], arow + mi * 16);                 \
  } while (0)
#define RD_AHI(buf) do {                                                      \
    _Pragma("unroll") for (int mi = 0; mi < 2; ++mi)                          \
      FRAGP(aHi[mi][0], aHi[mi][1], Ah[buf], arow + (2 + mi) * 16);           \
  } while (0)
#define RD_B01(buf) do {                                                      \
    _Pragma("unroll") for (int ni = 0; ni < 2; ++ni)                          \
      FRAGP(bLo[ni][0], bLo[ni][1], Bh[buf], brow + ni * 16);                 \
  } while (0)
#define RD_B23(buf) do {                                                      \
    _Pragma("unroll") for (int ni = 0; ni < 2; ++ni)                          \
      FRAGP(bHi[ni][0], bHi[ni][1], Bh[buf], brow + (2 + ni) * 16);           \
  } while (0)
  // quadrant MFMA: 8 x mfma_f32_16x16x32_fp8_fp8
#define MFMA_Q(AG, BG, MI0, NI0) do {                                         \
    __builtin_amdgcn_s_setprio(1);                                            \
    _Pragma("unroll") for (int kk = 0; kk < 2; ++kk)                          \
    _Pragma("unroll") for (int mi = 0; mi < 2; ++mi)                          \
    _Pragma("unroll") for (int ni = 0; ni < 2; ++ni)                          \
      acc[(MI0) + mi][(NI0) + ni] = __builtin_amdgcn_mfma_f32_16x16x32_fp8_fp8( \
          AG[mi][kk], BG[ni][kk], acc[(MI0) + mi][(NI0) + ni], 0, 0, 0);      \
    __builtin_amdgcn_s_setprio(0);                                            \
  } while (0)

  // One K-tile: compute tile in buf C (quadrant pipeline), stage tile ST into
  // buf (C+3)&3 mid-body, counted handoff, prefetch next tile's first frags.
#define TILE(C, CN, ST) do {                                                  \
    RD_B23(C); SCHED0();                                                      \
    MFMA_Q(aLo, bLo, 0, 0); SCHED0();                                         \
    STAGE_AB((C + 3) & 3, ST);                                                \
    RD_AHI(C); SCHED0();                                                      \
    MFMA_Q(aLo, bHi, 0, 2); SCHED0();                                         \
    MFMA_Q(aHi, bLo, 2, 0); SCHED0();                                         \
    VMCNT(4);                  /* next tile landed; 4 ops stay in flight */   \
    BAR(); SCHED0();                                                          \
    RD_ALO(CN); RD_B01(CN); SCHED0();                                         \
    MFMA_Q(aHi, bHi, 2, 2); SCHED0();                                         \
  } while (0)

  // ---- prologue: stage tiles 0,1,2 into bufs 0,1,2; open tile 0 ----
  STAGE_AB(0, 0);
  STAGE_AB(1, 1);
  STAGE_AB(2, 2);
  VMCNT(4);                      // tile0's 2 ops landed; tiles 1,2 in flight
  BAR(); SCHED0();
  RD_ALO(0); RD_B01(0);
  SCHED0();

  // ---- main loop: 8 iterations x 4 K-tiles (literal buffer indices) ----
  for (int i = 0; i < 8; ++i) {
    const int base = 4 * i;
    TILE(0, 1, base + 3);
    TILE(1, 2, base + 4);
    TILE(2, 3, base + 5);
    TILE(3, 0, base + 6);
  }
  VMCNT(0);                      // epilogue-only full drain
  BAR(); SCHED0();

  // ---- fused LSE epilogue over this block's 256 vocab cols ----
  // C/D layout: col = lane&15, row = (lane>>4)*4 + reg. Un-scale by INV_SC.
  float* red = (float*)&lds[0][0][0][0];   // m: [wn*256+row], s: [1024 + wn*256+row]
#pragma unroll
  for (int mi = 0; mi < 4; ++mi) {
#pragma unroll
    for (int r = 0; r < 4; ++r) {
      float v0 = acc[mi][0][r] * INV_SC;
      float v1 = acc[mi][1][r] * INV_SC;
      float v2 = acc[mi][2][r] * INV_SC;
      float v3 = acc[mi][3][r] * INV_SC;
      float m = fmaxf(fmaxf(v0, v1), fmaxf(v2, v3));
#pragma unroll
      for (int o = 1; o < 16; o <<= 1) m = fmaxf(m, __shfl_xor(m, o, 64));
      float s = __expf(v0 - m) + __expf(v1 - m) + __expf(v2 - m) + __expf(v3 - m);
#pragma unroll
      for (int o = 1; o < 16; o <<= 1) s += __shfl_xor(s, o, 64);
      if (l15 == 0) {
        int row = wm * 64 + mi * 16 + (lane >> 4) * 4 + r;
        red[wn * 256 + row] = m;
        red[1024 + wn * 256 + row] = s;
      }
    }
  }
  __syncthreads();
  if (tid < 256) {
    float m0 = red[tid], m1 = red[256 + tid], m2 = red[512 + tid], m3 = red[768 + tid];
    float M = fmaxf(fmaxf(m0, m1), fmaxf(m2, m3));
    float S = red[1024 + tid] * __expf(m0 - M) + red[1280 + tid] * __expf(m1 - M) +
              red[1536 + tid] * __expf(m2 - M) + red[1792 + tid] * __expf(m3 - M);
    pp[(size_t)(mb * 256 + tid) * NVB + nb] = make_float2(M, S);
  }
#undef STAGE_AB
#undef FRAGP
#undef RD_ALO
#undef RD_AHI
#undef RD_B01
#undef RD_B23
#undef MFMA_Q
#undef TILE
}

// ---------------------------------------------------------------- exact fp32 target logit: dot(x, W[y])
__global__ void target_logit(const float* __restrict__ x, const float* __restrict__ xr,
                             const float* __restrict__ W, const float* __restrict__ Wr,
                             const int* __restrict__ y, float* __restrict__ tlog) {
  int wid = (blockIdx.x * blockDim.x + threadIdx.x) >> 6;  // 0..8191
  int lane = threadIdx.x & 63;
  int which = wid >> 12;
  int tok = wid & 4095;
  int yy = y[tok];
  int ys = (yy == -100) ? 0 : yy;
  const float* xv = (which ? xr : x) + (size_t)tok * HDIM;
  const float* wv = (which ? Wr : W) + (size_t)ys * HDIM;
  const float4* x4 = (const float4*)xv;
  const float4* w4 = (const float4*)wv;
  float sum = 0.f;
  for (int i = lane; i < HDIM / 4; i += 64) {
    float4 a = x4[i], b = w4[i];
    sum += a.x * b.x + a.y * b.y + a.z * b.z + a.w * b.w;
  }
#pragma unroll
  for (int o = 1; o < 64; o <<= 1) sum += __shfl_xor(sum, o, 64);
  if (lane == 0) tlog[wid] = sum;
}

// ---------------------------------------------------------------- merge partials -> per-token logp
__global__ void lse_combine(const float2* __restrict__ part,
                            const float* __restrict__ tlog,
                            float* __restrict__ ptok) {
  int wid = (blockIdx.x * blockDim.x + threadIdx.x) >> 6;  // 0..8191
  int lane = threadIdx.x & 63;
  const float2* p = part + (size_t)wid * NVB;
  float m = -INFINITY, s = 0.f;
  for (int i = lane; i < NVB; i += 64) {
    float2 v = p[i];
    float M = fmaxf(m, v.x);
    s = s * __expf(m - M) + v.y * __expf(v.x - M);
    m = M;
  }
#pragma unroll
  for (int o = 1; o < 64; o <<= 1) {
    float mo = __shfl_xor(m, o, 64);
    float so = __shfl_xor(s, o, 64);
    float M = fmaxf(m, mo);
    s = s * __expf(m - M) + so * __expf(mo - M);
    m = M;
  }
  if (lane == 0) ptok[wid] = tlog[wid] - (m + logf(s));
}

// ---------------------------------------------------------------- masked per-seq mean + DPO loss
__global__ void final_loss(const float* __restrict__ ptok,
                           const int* __restrict__ y, float* __restrict__ out) {
  __shared__ float rs[256];
  __shared__ float rc[256];
  __shared__ float seq[8];
  int tid = threadIdx.x;
  for (int s = 0; s < 8; ++s) {
    int which = s >> 2, b = s & 3;
    float lsum = 0.f, lcnt = 0.f;
    for (int t = tid; t < 1024; t += 256) {
      int yy = y[b * 1024 + t];
      if (yy != -100) {
        lsum += ptok[which * 4096 + b * 1024 + t];
        lcnt += 1.f;
      }
    }
    rs[tid] = lsum; rc[tid] = lcnt;
    __syncthreads();
    for (int o = 128; o > 0; o >>= 1) {
      if (tid < o) { rs[tid] += rs[tid + o]; rc[tid] += rc[tid + o]; }
      __syncthreads();
    }
    if (tid == 0) seq[s] = rs[0] / rc[0];
    __syncthreads();
  }
  if (tid == 0) {
    float d0 = BETA_F * ((seq[0] - seq[4]) - (seq[2] - seq[6]));
    float d1 = BETA_F * ((seq[1] - seq[5]) - (seq[3] - seq[7]));
    auto sp = [](float a) { return fmaxf(a, 0.f) + log1pf(expf(-fabsf(a))); };
    out[0] = (sp(-d0) + sp(-d1)) * 0.5f;
  }
}

// ---------------------------------------------------------------- launch
extern "C" void kernel_launch(void* const* d_in, const int* in_sizes, int n_in,
                              void* d_out, int out_size, void* d_ws, size_t ws_size,
                              hipStream_t stream) {
  const float* x   = (const float*)d_in[0];
  const float* xr  = (const float*)d_in[1];
  const int*   y   = (const int*)d_in[2];
  const float* Wf  = (const float*)d_in[3];
  const float* Wrf = (const float*)d_in[4];
  float* out = (float*)d_out;

  char* ws = (char*)d_ws;
  size_t off = 0;
  auto alloc = [&](size_t bytes) -> void* {
    void* p = ws + off;
    off = (off + bytes + 255) & ~(size_t)255;
    return p;
  };
  unsigned char* Xq  = (unsigned char*)alloc((size_t)BT * HDIM);
  unsigned char* Xrq = (unsigned char*)alloc((size_t)BT * HDIM);
  unsigned char* Wq  = (unsigned char*)alloc((size_t)VOCAB * HDIM);
  unsigned char* Wrq = (unsigned char*)alloc((size_t)VOCAB * HDIM);
  float2* part = (float2*)alloc((size_t)2 * BT * NVB * sizeof(float2));
  float*  tlog = (float*)alloc((size_t)2 * BT * sizeof(float));
  float*  ptok = (float*)alloc((size_t)2 * BT * sizeof(float));

  cast_fp8_kernel<<<2048, 256, 0, stream>>>(x,  (uint4*)Xq,  BT * HDIM / 16, SCALE_X);
  cast_fp8_kernel<<<2048, 256, 0, stream>>>(xr, (uint4*)Xrq, BT * HDIM / 16, SCALE_X);
  cast_fp8_kernel<<<2048, 256, 0, stream>>>(Wf,  (uint4*)Wq,  VOCAB * HDIM / 16, SCALE_W);
  cast_fp8_kernel<<<2048, 256, 0, stream>>>(Wrf, (uint4*)Wrq, VOCAB * HDIM / 16, SCALE_W);

  dim3 gg(2000, 2);
  gemm_lse256<<<gg, 1024, 0, stream>>>(Xq, Xrq, Wq, Wrq, part);

  target_logit<<<2048, 256, 0, stream>>>(x, xr, Wf, Wrf, y, tlog);
  lse_combine<<<2048, 256, 0, stream>>>(part, tlog, ptok);
  final_loss<<<1, 256, 0, stream>>>(ptok, y, out);
}

// Round 14
// 951.185 us; speedup vs baseline: 1.1677x; 1.1677x over previous
//
#include <hip/hip_runtime.h>
#include <cstdint>
#include <cstddef>

#define HDIM 2048
#define VOCAB 32000
#define BT 4096      // B*T tokens
#define NVB 125      // VOCAB / 256
#define BETA_F 0.1f
#define SCALE_X 16.0f
#define SCALE_W 64.0f
#define INV_SC (1.0f / (SCALE_X * SCALE_W))

typedef float f32x4 __attribute__((ext_vector_type(4)));
typedef long lx2 __attribute__((ext_vector_type(2)));

// ---------------------------------------------------------------- helpers
__device__ __forceinline__ void async_lds16(const void* g, void* l) {
  __builtin_amdgcn_global_load_lds(
      (__attribute__((address_space(1))) void*)g,
      (__attribute__((address_space(3))) void*)l,
      16, 0, 0);
}

#define BAR() __builtin_amdgcn_s_barrier()
#define SCHED0() __builtin_amdgcn_sched_barrier(0)
#define VMCNT(n) do { asm volatile("s_waitcnt vmcnt(" #n ")" ::: "memory"); \
                      __builtin_amdgcn_sched_barrier(0); } while (0)

// ---------------------------------------------------------------- cast fp32 -> fp8 e4m3 (16 elems/thread), scaled
__global__ void cast_fp8_kernel(const float* __restrict__ src,
                                uint4* __restrict__ dst, int n16, float scale) {
  int i = blockIdx.x * blockDim.x + threadIdx.x;
  int stride = gridDim.x * blockDim.x;
  for (; i < n16; i += stride) {
    const float4* s = (const float4*)src + (size_t)i * 4;
    uint4 o;
    {
      float4 a = s[0];
      int r = __builtin_amdgcn_cvt_pk_fp8_f32(a.x * scale, a.y * scale, 0, false);
      o.x = __builtin_amdgcn_cvt_pk_fp8_f32(a.z * scale, a.w * scale, r, true);
    }
    {
      float4 a = s[1];
      int r = __builtin_amdgcn_cvt_pk_fp8_f32(a.x * scale, a.y * scale, 0, false);
      o.y = __builtin_amdgcn_cvt_pk_fp8_f32(a.z * scale, a.w * scale, r, true);
    }
    {
      float4 a = s[2];
      int r = __builtin_amdgcn_cvt_pk_fp8_f32(a.x * scale, a.y * scale, 0, false);
      o.z = __builtin_amdgcn_cvt_pk_fp8_f32(a.z * scale, a.w * scale, r, true);
    }
    {
      float4 a = s[3];
      int r = __builtin_amdgcn_cvt_pk_fp8_f32(a.x * scale, a.y * scale, 0, false);
      o.w = __builtin_amdgcn_cvt_pk_fp8_f32(a.z * scale, a.w * scale, r, true);
    }
    dst[i] = o;
  }
}

// ---------------------------------------------------------------- 256x256 fp8 GEMM + LSE partials, 16 waves, BK=128
// R11's verified 16-wave quadrant-pipelined schedule with BK doubled to 128:
// each LDS buffer holds TWO adjacent 64-K sub-slabs (layout per sub-slab is
// the R5/R9/R11-verified map, unchanged), so the mid-tile handoff disappears:
// 17 barriers total vs R11's 33. vmcnt(0)+BAR discipline kept (counted vmcnt
// regressed in R13; MX regressed in R12 -- both rejected).
//
// LDS sub-slab: [row(128)][4 chunks x 16B], chunk c of a row's 64-B K-slab =
// [kk0-slot-c | kk1-slot-c] (K-permutation; cancels between A and B). One
// ds_read_b128 per row yields both kk fragments, conflict-free (verified 0).
// Swizzle: physical ^= ((row>>3)&1)<<5; staging source pre-swizzled.
// Wave w stages rows (w>>3)*128 + (w&7)*16.. -> granule w*1024 per 16KB region.
//
// WAR: the buffer staged during super-iter i was fully read in super-iter i-1,
// and those reads retired before the i-1 barrier -> staging after it is safe.
// Sub0->sub1 within a buffer needs no sync (landed before buffer's barrier).
//
// NOTE 1024-thread block REQUIRES <=128 VGPR/wave. Spill tripwire:
// WRITE_SIZE balloons (R4/R8). No VGPR cap beyond the block size.
__global__ __launch_bounds__(1024) void gemm_lse256(
    const unsigned char* __restrict__ Xq,
    const unsigned char* __restrict__ Xrq,
    const unsigned char* __restrict__ Wq,
    const unsigned char* __restrict__ Wrq,
    float2* __restrict__ part) {
  __shared__ __align__(16) char lds[2][2][2][16384];  // [buf][A/B][sub][2 halves x 8KB]

  const int tid = threadIdx.x;
  const int lane = tid & 63;
  const int w = tid >> 6;        // wave 0..15
  const int wm = w >> 2;         // 0..3 : M 64-row band
  const int wn = w & 3;          // 0..3 : N 64-col band
  const int which = blockIdx.y;  // 0 = policy, 1 = reference

  // XCD-aware bijective swizzle: 2000 blocks = 8 XCDs x 250, mb fastest within chunk.
  const int lin = blockIdx.x;
  const int nl = (lin & 7) * 250 + (lin >> 3);
  const int mb = nl & 15;        // 0..15
  const int nb = nl >> 4;        // 0..124

  const unsigned char* A = which ? Xrq : Xq;
  const unsigned char* B = which ? Wrq : Wq;
  float2* pp = part + (size_t)which * BT * NVB;

  // ---- staging addressing (source pre-swizzled to undo read-side XOR) ----
  const int lanep = lane ^ ((lane & 32) >> 4);
  const int srow = (w >> 3) * 128 + (w & 7) * 16 + (lanep >> 2);  // row in 256-row tile
  const int scol = (lanep & 3) * 16;                              // byte col in 64-B K-slab
  const unsigned char* Ag = A + (size_t)(mb * 256 + srow) * HDIM + scol;
  const unsigned char* Bg = B + (size_t)(nb * 256 + srow) * HDIM + scol;

  // super-tile T (BK=128) = 64-K slabs {2T, 2T+1} -> subs {0, 1}
#define STAGE4(buf, T) do {                                                   \
    async_lds16(Ag + (size_t)(2 * (T)) * 64,     &lds[buf][0][0][0] + w * 1024); \
    async_lds16(Ag + (size_t)(2 * (T) + 1) * 64, &lds[buf][0][1][0] + w * 1024); \
    async_lds16(Bg + (size_t)(2 * (T)) * 64,     &lds[buf][1][0][0] + w * 1024); \
    async_lds16(Bg + (size_t)(2 * (T) + 1) * 64, &lds[buf][1][1][0] + w * 1024); \
  } while (0)

  // ---- paired fragment read (swizzled b128 -> kk0 + kk1), verified ----
  const int l15 = lane & 15;
  const int kbyte = (lane >> 4) * 16;
#define FRAGP(d0, d1, halfptr, row) do {                                      \
    int _r = (row);                                                           \
    int _L = _r * 64 + kbyte;                                                 \
    lx2 _v = *(const lx2*)((halfptr) + (_L ^ (((_r >> 3) & 1) << 5)));        \
    d0 = _v.x; d1 = _v.y;                                                     \
  } while (0)

  const int ahalf = (wm >> 1) * 8192;
  const int bhalf = (wn >> 1) * 8192;
#define APTR(buf, sub) (&lds[buf][0][sub][0] + ahalf)
#define BPTR(buf, sub) (&lds[buf][1][sub][0] + bhalf)
  const int arow = (wm & 1) * 64 + l15;
  const int brow = (wn & 1) * 64 + l15;

  f32x4 acc[4][4] = {};
  long aLo[2][2], aHi[2][2], bLo[2][2], bHi[2][2];

#define RD_ALO(buf, sub) do {                                                 \
    _Pragma("unroll") for (int mi = 0; mi < 2; ++mi)                          \
      FRAGP(aLo[mi][0], aLo[mi][1], APTR(buf, sub), arow + mi * 16);          \
  } while (0)
#define RD_AHI(buf, sub) do {                                                 \
    _Pragma("unroll") for (int mi = 0; mi < 2; ++mi)                          \
      FRAGP(aHi[mi][0], aHi[mi][1], APTR(buf, sub), arow + (2 + mi) * 16);    \
  } while (0)
#define RD_B01(buf, sub) do {                                                 \
    _Pragma("unroll") for (int ni = 0; ni < 2; ++ni)                          \
      FRAGP(bLo[ni][0], bLo[ni][1], BPTR(buf, sub), brow + ni * 16);          \
  } while (0)
#define RD_B23(buf, sub) do {                                                 \
    _Pragma("unroll") for (int ni = 0; ni < 2; ++ni)                          \
      FRAGP(bHi[ni][0], bHi[ni][1], BPTR(buf, sub), brow + (2 + ni) * 16);    \
  } while (0)
  // quadrant MFMA: 8 x mfma_f32_16x16x32_fp8_fp8
#define MFMA_Q(AG, BG, MI0, NI0) do {                                         \
    __builtin_amdgcn_s_setprio(1);                                            \
    _Pragma("unroll") for (int kk = 0; kk < 2; ++kk)                          \
    _Pragma("unroll") for (int mi = 0; mi < 2; ++mi)                          \
    _Pragma("unroll") for (int ni = 0; ni < 2; ++ni)                          \
      acc[(MI0) + mi][(NI0) + ni] = __builtin_amdgcn_mfma_f32_16x16x32_fp8_fp8( \
          AG[mi][kk], BG[ni][kk], acc[(MI0) + mi][(NI0) + ni], 0, 0, 0);      \
    __builtin_amdgcn_s_setprio(0);                                            \
  } while (0)

  // One super-iter: compute buf C (subs 0,1; aLo/bLo of sub0 prefetched),
  // stage super-tile T into buf NB early, single handoff at the end.
#define SUPER(C, NB, T) do {                                                  \
    STAGE4(NB, T); SCHED0();                                                  \
    RD_B23(C, 0); SCHED0();                                                   \
    MFMA_Q(aLo, bLo, 0, 0); SCHED0();                                         \
    RD_AHI(C, 0); SCHED0();                                                   \
    MFMA_Q(aLo, bHi, 0, 2); SCHED0();                                         \
    MFMA_Q(aHi, bLo, 2, 0); SCHED0();                                         \
    RD_ALO(C, 1); RD_B01(C, 1); SCHED0();                                     \
    MFMA_Q(aHi, bHi, 2, 2); SCHED0();                                         \
    RD_B23(C, 1); SCHED0();                                                   \
    MFMA_Q(aLo, bLo, 0, 0); SCHED0();                                         \
    RD_AHI(C, 1); SCHED0();                                                   \
    MFMA_Q(aLo, bHi, 0, 2); SCHED0();                                         \
    MFMA_Q(aHi, bLo, 2, 0); SCHED0();                                         \
    VMCNT(0);                                                                 \
    BAR(); SCHED0();                                                          \
    RD_ALO(NB, 0); RD_B01(NB, 0); SCHED0();                                   \
    MFMA_Q(aHi, bHi, 2, 2); SCHED0();                                         \
  } while (0)

  // ---- prologue: stage super-tile 0 into buf0; open it ----
  STAGE4(0, 0);
  VMCNT(0);
  BAR(); SCHED0();
  RD_ALO(0, 0); RD_B01(0, 0);
  SCHED0();

  // ---- main loop: 16 super-tiles (K = 16 x 128), literal buffer indices ----
  for (int j = 0; j < 8; ++j) {
    const int t1 = 2 * j + 1;
    const int t2 = (2 * j + 2 > 15) ? 15 : 2 * j + 2;  // tail restage = same bytes
    SUPER(0, 1, t1);
    SUPER(1, 0, t2);
  }
  VMCNT(0);                      // drain tail re-stage before LDS reuse
  BAR(); SCHED0();

  // ---- fused LSE epilogue over this block's 256 vocab cols ----
  // C/D layout: col = lane&15, row = (lane>>4)*4 + reg. Un-scale by INV_SC.
  float* red = (float*)&lds[0][0][0][0];   // m: [wn*256+row], s: [1024 + wn*256+row]
#pragma unroll
  for (int mi = 0; mi < 4; ++mi) {
#pragma unroll
    for (int r = 0; r < 4; ++r) {
      float v0 = acc[mi][0][r] * INV_SC;
      float v1 = acc[mi][1][r] * INV_SC;
      float v2 = acc[mi][2][r] * INV_SC;
      float v3 = acc[mi][3][r] * INV_SC;
      float m = fmaxf(fmaxf(v0, v1), fmaxf(v2, v3));
#pragma unroll
      for (int o = 1; o < 16; o <<= 1) m = fmaxf(m, __shfl_xor(m, o, 64));
      float s = __expf(v0 - m) + __expf(v1 - m) + __expf(v2 - m) + __expf(v3 - m);
#pragma unroll
      for (int o = 1; o < 16; o <<= 1) s += __shfl_xor(s, o, 64);
      if (l15 == 0) {
        int row = wm * 64 + mi * 16 + (lane >> 4) * 4 + r;
        red[wn * 256 + row] = m;
        red[1024 + wn * 256 + row] = s;
      }
    }
  }
  __syncthreads();
  if (tid < 256) {
    float m0 = red[tid], m1 = red[256 + tid], m2 = red[512 + tid], m3 = red[768 + tid];
    float M = fmaxf(fmaxf(m0, m1), fmaxf(m2, m3));
    float S = red[1024 + tid] * __expf(m0 - M) + red[1280 + tid] * __expf(m1 - M) +
              red[1536 + tid] * __expf(m2 - M) + red[1792 + tid] * __expf(m3 - M);
    pp[(size_t)(mb * 256 + tid) * NVB + nb] = make_float2(M, S);
  }
#undef STAGE4
#undef FRAGP
#undef APTR
#undef BPTR
#undef RD_ALO
#undef RD_AHI
#undef RD_B01
#undef RD_B23
#undef MFMA_Q
#undef SUPER
}

// ---------------------------------------------------------------- exact fp32 target logit: dot(x, W[y])
__global__ void target_logit(const float* __restrict__ x, const float* __restrict__ xr,
                             const float* __restrict__ W, const float* __restrict__ Wr,
                             const int* __restrict__ y, float* __restrict__ tlog) {
  int wid = (blockIdx.x * blockDim.x + threadIdx.x) >> 6;  // 0..8191
  int lane = threadIdx.x & 63;
  int which = wid >> 12;
  int tok = wid & 4095;
  int yy = y[tok];
  int ys = (yy == -100) ? 0 : yy;
  const float* xv = (which ? xr : x) + (size_t)tok * HDIM;
  const float* wv = (which ? Wr : W) + (size_t)ys * HDIM;
  const float4* x4 = (const float4*)xv;
  const float4* w4 = (const float4*)wv;
  float sum = 0.f;
  for (int i = lane; i < HDIM / 4; i += 64) {
    float4 a = x4[i], b = w4[i];
    sum += a.x * b.x + a.y * b.y + a.z * b.z + a.w * b.w;
  }
#pragma unroll
  for (int o = 1; o < 64; o <<= 1) sum += __shfl_xor(sum, o, 64);
  if (lane == 0) tlog[wid] = sum;
}

// ---------------------------------------------------------------- merge partials -> per-token logp
__global__ void lse_combine(const float2* __restrict__ part,
                            const float* __restrict__ tlog,
                            float* __restrict__ ptok) {
  int wid = (blockIdx.x * blockDim.x + threadIdx.x) >> 6;  // 0..8191
  int lane = threadIdx.x & 63;
  const float2* p = part + (size_t)wid * NVB;
  float m = -INFINITY, s = 0.f;
  for (int i = lane; i < NVB; i += 64) {
    float2 v = p[i];
    float M = fmaxf(m, v.x);
    s = s * __expf(m - M) + v.y * __expf(v.x - M);
    m = M;
  }
#pragma unroll
  for (int o = 1; o < 64; o <<= 1) {
    float mo = __shfl_xor(m, o, 64);
    float so = __shfl_xor(s, o, 64);
    float M = fmaxf(m, mo);
    s = s * __expf(m - M) + so * __expf(mo - M);
    m = M;
  }
  if (lane == 0) ptok[wid] = tlog[wid] - (m + logf(s));
}

// ---------------------------------------------------------------- masked per-seq mean + DPO loss
__global__ void final_loss(const float* __restrict__ ptok,
                           const int* __restrict__ y, float* __restrict__ out) {
  __shared__ float rs[256];
  __shared__ float rc[256];
  __shared__ float seq[8];
  int tid = threadIdx.x;
  for (int s = 0; s < 8; ++s) {
    int which = s >> 2, b = s & 3;
    float lsum = 0.f, lcnt = 0.f;
    for (int t = tid; t < 1024; t += 256) {
      int yy = y[b * 1024 + t];
      if (yy != -100) {
        lsum += ptok[which * 4096 + b * 1024 + t];
        lcnt += 1.f;
      }
    }
    rs[tid] = lsum; rc[tid] = lcnt;
    __syncthreads();
    for (int o = 128; o > 0; o >>= 1) {
      if (tid < o) { rs[tid] += rs[tid + o]; rc[tid] += rc[tid + o]; }
      __syncthreads();
    }
    if (tid == 0) seq[s] = rs[0] / rc[0];
    __syncthreads();
  }
  if (tid == 0) {
    float d0 = BETA_F * ((seq[0] - seq[4]) - (seq[2] - seq[6]));
    float d1 = BETA_F * ((seq[1] - seq[5]) - (seq[3] - seq[7]));
    auto sp = [](float a) { return fmaxf(a, 0.f) + log1pf(expf(-fabsf(a))); };
    out[0] = (sp(-d0) + sp(-d1)) * 0.5f;
  }
}

// ---------------------------------------------------------------- launch
extern "C" void kernel_launch(void* const* d_in, const int* in_sizes, int n_in,
                              void* d_out, int out_size, void* d_ws, size_t ws_size,
                              hipStream_t stream) {
  const float* x   = (const float*)d_in[0];
  const float* xr  = (const float*)d_in[1];
  const int*   y   = (const int*)d_in[2];
  const float* Wf  = (const float*)d_in[3];
  const float* Wrf = (const float*)d_in[4];
  float* out = (float*)d_out;

  char* ws = (char*)d_ws;
  size_t off = 0;
  auto alloc = [&](size_t bytes) -> void* {
    void* p = ws + off;
    off = (off + bytes + 255) & ~(size_t)255;
    return p;
  };
  unsigned char* Xq  = (unsigned char*)alloc((size_t)BT * HDIM);
  unsigned char* Xrq = (unsigned char*)alloc((size_t)BT * HDIM);
  unsigned char* Wq  = (unsigned char*)alloc((size_t)VOCAB * HDIM);
  unsigned char* Wrq = (unsigned char*)alloc((size_t)VOCAB * HDIM);
  float2* part = (float2*)alloc((size_t)2 * BT * NVB * sizeof(float2));
  float*  tlog = (float*)alloc((size_t)2 * BT * sizeof(float));
  float*  ptok = (float*)alloc((size_t)2 * BT * sizeof(float));

  cast_fp8_kernel<<<2048, 256, 0, stream>>>(x,  (uint4*)Xq,  BT * HDIM / 16, SCALE_X);
  cast_fp8_kernel<<<2048, 256, 0, stream>>>(xr, (uint4*)Xrq, BT * HDIM / 16, SCALE_X);
  cast_fp8_kernel<<<2048, 256, 0, stream>>>(Wf,  (uint4*)Wq,  VOCAB * HDIM / 16, SCALE_W);
  cast_fp8_kernel<<<2048, 256, 0, stream>>>(Wrf, (uint4*)Wrq, VOCAB * HDIM / 16, SCALE_W);

  dim3 gg(2000, 2);
  gemm_lse256<<<gg, 1024, 0, stream>>>(Xq, Xrq, Wq, Wrq, part);

  target_logit<<<2048, 256, 0, stream>>>(x, xr, Wf, Wrf, y, tlog);
  lse_combine<<<2048, 256, 0, stream>>>(part, tlog, ptok);
  final_loss<<<1, 256, 0, stream>>>(ptok, y, out);
}

// Round 15
// 932.271 us; speedup vs baseline: 1.1914x; 1.0203x over previous
//
#include <hip/hip_runtime.h>
#include <cstdint>
#include <cstddef>

#define HDIM 2048
#define VOCAB 32000
#define BT 4096      // B*T tokens
#define NVB 125      // VOCAB / 256
#define BETA_F 0.1f
#define SCALE_X 16.0f
#define SCALE_W 64.0f
#define INV_SC (1.0f / (SCALE_X * SCALE_W))

typedef float f32x4 __attribute__((ext_vector_type(4)));
typedef long lx2 __attribute__((ext_vector_type(2)));

// ---------------------------------------------------------------- helpers
__device__ __forceinline__ void async_lds16(const void* g, void* l) {
  __builtin_amdgcn_global_load_lds(
      (__attribute__((address_space(1))) void*)g,
      (__attribute__((address_space(3))) void*)l,
      16, 0, 0);
}

#define BAR() __builtin_amdgcn_s_barrier()
#define SCHED0() __builtin_amdgcn_sched_barrier(0)
#define VMCNT(n) do { asm volatile("s_waitcnt vmcnt(" #n ")" ::: "memory"); \
                      __builtin_amdgcn_sched_barrier(0); } while (0)

// ---------------------------------------------------------------- fused cast fp32 -> fp8 e4m3 (all 4 arrays)
__global__ void cast_all_fp8(const float* __restrict__ x, const float* __restrict__ xr,
                             const float* __restrict__ Wf, const float* __restrict__ Wrf,
                             uint4* __restrict__ Xq, uint4* __restrict__ Xrq,
                             uint4* __restrict__ Wq, uint4* __restrict__ Wrq) {
  const int NX = BT * HDIM / 16;      // 524288 groups of 16
  const int NW = VOCAB * HDIM / 16;   // 4096000 groups of 16
  const int total = 2 * NX + 2 * NW;
  int i = blockIdx.x * blockDim.x + threadIdx.x;
  int stride = gridDim.x * blockDim.x;
  for (; i < total; i += stride) {
    const float* src; uint4* dst; float scale; int j;
    if (i < 2 * NX) {
      scale = SCALE_X;
      if (i < NX) { src = x;  dst = Xq;  j = i; }
      else        { src = xr; dst = Xrq; j = i - NX; }
    } else {
      scale = SCALE_W;
      int k = i - 2 * NX;
      if (k < NW) { src = Wf;  dst = Wq;  j = k; }
      else        { src = Wrf; dst = Wrq; j = k - NW; }
    }
    const float4* s = (const float4*)src + (size_t)j * 4;
    uint4 o;
    {
      float4 a = s[0];
      int r = __builtin_amdgcn_cvt_pk_fp8_f32(a.x * scale, a.y * scale, 0, false);
      o.x = __builtin_amdgcn_cvt_pk_fp8_f32(a.z * scale, a.w * scale, r, true);
    }
    {
      float4 a = s[1];
      int r = __builtin_amdgcn_cvt_pk_fp8_f32(a.x * scale, a.y * scale, 0, false);
      o.y = __builtin_amdgcn_cvt_pk_fp8_f32(a.z * scale, a.w * scale, r, true);
    }
    {
      float4 a = s[2];
      int r = __builtin_amdgcn_cvt_pk_fp8_f32(a.x * scale, a.y * scale, 0, false);
      o.z = __builtin_amdgcn_cvt_pk_fp8_f32(a.z * scale, a.w * scale, r, true);
    }
    {
      float4 a = s[3];
      int r = __builtin_amdgcn_cvt_pk_fp8_f32(a.x * scale, a.y * scale, 0, false);
      o.w = __builtin_amdgcn_cvt_pk_fp8_f32(a.z * scale, a.w * scale, r, true);
    }
    dst[j] = o;
  }
}

// ---------------------------------------------------------------- 256x256 fp8 GEMM + LSE partials, 16 waves
// R11 VERBATIM (the 814 us / absmax-0 best): 16 waves (4 waves/SIMD soak
// handoff stalls in-workgroup), wave-tile 64x64, quadrant-pipelined reads,
// 2 barriers per K-tile with vmcnt(0) handoffs. Schedule-level variants all
// rejected by measurement: MX 2x-rate (R12: -4%), counted vmcnt 4-buf (R13:
// -22%), BK=128 (R14: -2%). This is the structure-class plateau (59% MfmaUtil,
// 64% of the 2.05 PF fp8 MFMA ceiling; cf. m201 = 62% of its ceiling).
//
// LDS half-tile: [row(128)][4 chunks x 16B], chunk c of a row's 64-B K-slab =
// [kk0-slot-c | kk1-slot-c] (K-permutation; cancels between A and B). One
// ds_read_b128 per row yields both kk fragments, conflict-free (verified 0).
// Swizzle: physical ^= ((row>>3)&1)<<5; staging source pre-swizzled.
// Wave w stages rows (w>>3)*128 + (w&7)*16.. -> granule w*1024 per half-pair.
//
// NOTE 1024-thread block REQUIRES <=128 VGPR/wave (achieved: 64). Capping
// VGPRs below acc footprint spills to scratch (R4/R8: 5-37 GB, 5-6x slower).
__global__ __launch_bounds__(1024) void gemm_lse256(
    const unsigned char* __restrict__ Xq,
    const unsigned char* __restrict__ Xrq,
    const unsigned char* __restrict__ Wq,
    const unsigned char* __restrict__ Wrq,
    float2* __restrict__ part) {
  __shared__ __align__(16) char lds[2][2][2][8192];  // [buf][A/B][half]

  const int tid = threadIdx.x;
  const int lane = tid & 63;
  const int w = tid >> 6;        // wave 0..15
  const int wm = w >> 2;         // 0..3 : M 64-row band
  const int wn = w & 3;          // 0..3 : N 64-col band
  const int which = blockIdx.y;  // 0 = policy, 1 = reference

  // XCD-aware bijective swizzle: 2000 blocks = 8 XCDs x 250, mb fastest within chunk.
  const int lin = blockIdx.x;
  const int nl = (lin & 7) * 250 + (lin >> 3);
  const int mb = nl & 15;        // 0..15
  const int nb = nl >> 4;        // 0..124

  const unsigned char* A = which ? Xrq : Xq;
  const unsigned char* B = which ? Wrq : Wq;
  float2* pp = part + (size_t)which * BT * NVB;

  // ---- staging addressing (source pre-swizzled to undo read-side XOR) ----
  const int lanep = lane ^ ((lane & 32) >> 4);
  const int srow = (w >> 3) * 128 + (w & 7) * 16 + (lanep >> 2);  // row in 256-row tile
  const int scol = (lanep & 3) * 16;                              // byte col in 64-B K-slab
  const unsigned char* Ag = A + (size_t)(mb * 256 + srow) * HDIM + scol;
  const unsigned char* Bg = B + (size_t)(nb * 256 + srow) * HDIM + scol;

#define STAGE_AB(buf, T) do {                                                 \
    async_lds16(Ag + (size_t)(T) * 64, &lds[buf][0][0][0] + w * 1024);        \
    async_lds16(Bg + (size_t)(T) * 64, &lds[buf][1][0][0] + w * 1024);        \
  } while (0)

  // ---- paired fragment read (swizzled b128 -> kk0 + kk1), verified 0-conflict ----
  const int l15 = lane & 15;
  const int kbyte = (lane >> 4) * 16;
#define FRAGP(d0, d1, halfptr, row) do {                                      \
    int _r = (row);                                                           \
    int _L = _r * 64 + kbyte;                                                 \
    lx2 _v = *(const lx2*)((halfptr) + (_L ^ (((_r >> 3) & 1) << 5)));        \
    d0 = _v.x; d1 = _v.y;                                                     \
  } while (0)

  const char* Ah[2] = { &lds[0][0][wm >> 1][0], &lds[1][0][wm >> 1][0] };
  const char* Bh[2] = { &lds[0][1][wn >> 1][0], &lds[1][1][wn >> 1][0] };
  const int arow = (wm & 1) * 64 + l15;
  const int brow = (wn & 1) * 64 + l15;

  f32x4 acc[4][4] = {};
  long aLo[2][2], aHi[2][2], bLo[2][2], bHi[2][2];

#define RD_ALO(buf) do {                                                      \
    _Pragma("unroll") for (int mi = 0; mi < 2; ++mi)                          \
      FRAGP(aLo[mi][0], aLo[mi][1], Ah[buf], arow + mi * 16);                 \
  } while (0)
#define RD_AHI(buf) do {                                                      \
    _Pragma("unroll") for (int mi = 0; mi < 2; ++mi)                          \
      FRAGP(aHi[mi][0], aHi[mi][1], Ah[buf], arow + (2 + mi) * 16);           \
  } while (0)
#define RD_B01(buf) do {                                                      \
    _Pragma("unroll") for (int ni = 0; ni < 2; ++ni)                          \
      FRAGP(bLo[ni][0], bLo[ni][1], Bh[buf], brow + ni * 16);                 \
  } while (0)
#define RD_B23(buf) do {                                                      \
    _Pragma("unroll") for (int ni = 0; ni < 2; ++ni)                          \
      FRAGP(bHi[ni][0], bHi[ni][1], Bh[buf], brow + (2 + ni) * 16);           \
  } while (0)
  // quadrant MFMA: 8 x mfma_f32_16x16x32_fp8_fp8
#define MFMA_Q(AG, BG, MI0, NI0) do {                                         \
    __builtin_amdgcn_s_setprio(1);                                            \
    _Pragma("unroll") for (int kk = 0; kk < 2; ++kk)                          \
    _Pragma("unroll") for (int mi = 0; mi < 2; ++mi)                          \
    _Pragma("unroll") for (int ni = 0; ni < 2; ++ni)                          \
      acc[(MI0) + mi][(NI0) + ni] = __builtin_amdgcn_mfma_f32_16x16x32_fp8_fp8( \
          AG[mi][kk], BG[ni][kk], acc[(MI0) + mi][(NI0) + ni], 0, 0, 0);      \
    __builtin_amdgcn_s_setprio(0);                                            \
  } while (0)

  // ---- prologue: stage tiles 0 (buf0) and 1 (buf1); prefetch Q1(t0) ----
  STAGE_AB(0, 0);
  STAGE_AB(1, 1);
  VMCNT(2);                      // tile0's 2 ops landed (tile1's 2 in flight)
  BAR(); SCHED0();
  RD_ALO(0); RD_B01(0);
  SCHED0();

  // ---- main loop: 16 iterations, 2 K-tiles each ----
  for (int i = 0; i < 16; ++i) {
    const int se = (2 * i + 2 > 30) ? 30 : 2 * i + 2;  // even tile -> buf0
    const int so = (2 * i + 3 > 31) ? 31 : 2 * i + 3;  // odd  tile -> buf1

    // P1: issue bHi(t0); MFMA Q1(t0)
    RD_B23(0); SCHED0();
    MFMA_Q(aLo, bLo, 0, 0); SCHED0();
    // P2: issue aHi(t0); MFMA Q2(t0)
    RD_AHI(0); SCHED0();
    MFMA_Q(aLo, bHi, 0, 2); SCHED0();
    // P3: MFMA Q3(t0)
    MFMA_Q(aHi, bLo, 2, 0); SCHED0();
    // P4: handoff -> buf1 (t1's stages landed; buf0 reads retired => stage se)
    VMCNT(0);
    BAR(); SCHED0();
    STAGE_AB(0, se);
    RD_ALO(1); RD_B01(1); SCHED0();
    MFMA_Q(aHi, bHi, 2, 2); SCHED0();          // operands already in regs

    // P5: issue bHi(t1); MFMA Q1(t1)
    RD_B23(1); SCHED0();
    MFMA_Q(aLo, bLo, 0, 0); SCHED0();
    // P6: issue aHi(t1); MFMA Q2(t1)
    RD_AHI(1); SCHED0();
    MFMA_Q(aLo, bHi, 0, 2); SCHED0();
    // P7: MFMA Q3(t1)
    MFMA_Q(aHi, bLo, 2, 0); SCHED0();
    // P8: handoff -> buf0 (se's stages landed; buf1 reads retired => stage so)
    VMCNT(0);
    BAR(); SCHED0();
    STAGE_AB(1, so);
    RD_ALO(0); RD_B01(0); SCHED0();
    MFMA_Q(aHi, bHi, 2, 2); SCHED0();
  }
  VMCNT(0);                      // drain tail re-stages before LDS reuse
  BAR(); SCHED0();

  // ---- fused LSE epilogue over this block's 256 vocab cols ----
  // C/D layout: col = lane&15, row = (lane>>4)*4 + reg. Un-scale by INV_SC.
  float* red = (float*)&lds[0][0][0][0];   // m: [wn*256+row], s: [1024 + wn*256+row]
#pragma unroll
  for (int mi = 0; mi < 4; ++mi) {
#pragma unroll
    for (int r = 0; r < 4; ++r) {
      float v0 = acc[mi][0][r] * INV_SC;
      float v1 = acc[mi][1][r] * INV_SC;
      float v2 = acc[mi][2][r] * INV_SC;
      float v3 = acc[mi][3][r] * INV_SC;
      float m = fmaxf(fmaxf(v0, v1), fmaxf(v2, v3));
#pragma unroll
      for (int o = 1; o < 16; o <<= 1) m = fmaxf(m, __shfl_xor(m, o, 64));
      float s = __expf(v0 - m) + __expf(v1 - m) + __expf(v2 - m) + __expf(v3 - m);
#pragma unroll
      for (int o = 1; o < 16; o <<= 1) s += __shfl_xor(s, o, 64);
      if (l15 == 0) {
        int row = wm * 64 + mi * 16 + (lane >> 4) * 4 + r;
        red[wn * 256 + row] = m;
        red[1024 + wn * 256 + row] = s;
      }
    }
  }
  __syncthreads();
  if (tid < 256) {
    float m0 = red[tid], m1 = red[256 + tid], m2 = red[512 + tid], m3 = red[768 + tid];
    float M = fmaxf(fmaxf(m0, m1), fmaxf(m2, m3));
    float S = red[1024 + tid] * __expf(m0 - M) + red[1280 + tid] * __expf(m1 - M) +
              red[1536 + tid] * __expf(m2 - M) + red[1792 + tid] * __expf(m3 - M);
    pp[(size_t)(mb * 256 + tid) * NVB + nb] = make_float2(M, S);
  }
#undef STAGE_AB
#undef FRAGP
#undef RD_ALO
#undef RD_AHI
#undef RD_B01
#undef RD_B23
#undef MFMA_Q
}

// ---------------------------------------------------------------- fused: exact fp32 target logit + LSE merge
__global__ void lse_combine_fused(const float* __restrict__ x, const float* __restrict__ xr,
                                  const float* __restrict__ W, const float* __restrict__ Wr,
                                  const int* __restrict__ y, const float2* __restrict__ part,
                                  float* __restrict__ ptok) {
  int wid = (blockIdx.x * blockDim.x + threadIdx.x) >> 6;  // 0..8191
  int lane = threadIdx.x & 63;
  int which = wid >> 12;
  int tok = wid & 4095;
  int yy = y[tok];
  int ys = (yy == -100) ? 0 : yy;
  const float4* x4 = (const float4*)((which ? xr : x) + (size_t)tok * HDIM);
  const float4* w4 = (const float4*)((which ? Wr : W) + (size_t)ys * HDIM);
  float sum = 0.f;
  for (int i = lane; i < HDIM / 4; i += 64) {
    float4 a = x4[i], b = w4[i];
    sum += a.x * b.x + a.y * b.y + a.z * b.z + a.w * b.w;
  }
#pragma unroll
  for (int o = 1; o < 64; o <<= 1) sum += __shfl_xor(sum, o, 64);

  const float2* p = part + (size_t)wid * NVB;
  float m = -INFINITY, s = 0.f;
  for (int i = lane; i < NVB; i += 64) {
    float2 v = p[i];
    float M = fmaxf(m, v.x);
    s = s * __expf(m - M) + v.y * __expf(v.x - M);
    m = M;
  }
#pragma unroll
  for (int o = 1; o < 64; o <<= 1) {
    float mo = __shfl_xor(m, o, 64);
    float so = __shfl_xor(s, o, 64);
    float M = fmaxf(m, mo);
    s = s * __expf(m - M) + so * __expf(mo - M);
    m = M;
  }
  if (lane == 0) ptok[wid] = sum - (m + logf(s));
}

// ---------------------------------------------------------------- masked per-seq mean + DPO loss
__global__ void final_loss(const float* __restrict__ ptok,
                           const int* __restrict__ y, float* __restrict__ out) {
  __shared__ float rs[256];
  __shared__ float rc[256];
  __shared__ float seq[8];
  int tid = threadIdx.x;
  for (int s = 0; s < 8; ++s) {
    int which = s >> 2, b = s & 3;
    float lsum = 0.f, lcnt = 0.f;
    for (int t = tid; t < 1024; t += 256) {
      int yy = y[b * 1024 + t];
      if (yy != -100) {
        lsum += ptok[which * 4096 + b * 1024 + t];
        lcnt += 1.f;
      }
    }
    rs[tid] = lsum; rc[tid] = lcnt;
    __syncthreads();
    for (int o = 128; o > 0; o >>= 1) {
      if (tid < o) { rs[tid] += rs[tid + o]; rc[tid] += rc[tid + o]; }
      __syncthreads();
    }
    if (tid == 0) seq[s] = rs[0] / rc[0];
    __syncthreads();
  }
  if (tid == 0) {
    float d0 = BETA_F * ((seq[0] - seq[4]) - (seq[2] - seq[6]));
    float d1 = BETA_F * ((seq[1] - seq[5]) - (seq[3] - seq[7]));
    auto sp = [](float a) { return fmaxf(a, 0.f) + log1pf(expf(-fabsf(a))); };
    out[0] = (sp(-d0) + sp(-d1)) * 0.5f;
  }
}

// ---------------------------------------------------------------- launch
extern "C" void kernel_launch(void* const* d_in, const int* in_sizes, int n_in,
                              void* d_out, int out_size, void* d_ws, size_t ws_size,
                              hipStream_t stream) {
  const float* x   = (const float*)d_in[0];
  const float* xr  = (const float*)d_in[1];
  const int*   y   = (const int*)d_in[2];
  const float* Wf  = (const float*)d_in[3];
  const float* Wrf = (const float*)d_in[4];
  float* out = (float*)d_out;

  char* ws = (char*)d_ws;
  size_t off = 0;
  auto alloc = [&](size_t bytes) -> void* {
    void* p = ws + off;
    off = (off + bytes + 255) & ~(size_t)255;
    return p;
  };
  unsigned char* Xq  = (unsigned char*)alloc((size_t)BT * HDIM);
  unsigned char* Xrq = (unsigned char*)alloc((size_t)BT * HDIM);
  unsigned char* Wq  = (unsigned char*)alloc((size_t)VOCAB * HDIM);
  unsigned char* Wrq = (unsigned char*)alloc((size_t)VOCAB * HDIM);
  float2* part = (float2*)alloc((size_t)2 * BT * NVB * sizeof(float2));
  float*  ptok = (float*)alloc((size_t)2 * BT * sizeof(float));

  cast_all_fp8<<<2048, 256, 0, stream>>>(x, xr, Wf, Wrf,
                                         (uint4*)Xq, (uint4*)Xrq,
                                         (uint4*)Wq, (uint4*)Wrq);

  dim3 gg(2000, 2);
  gemm_lse256<<<gg, 1024, 0, stream>>>(Xq, Xrq, Wq, Wrq, part);

  lse_combine_fused<<<2048, 256, 0, stream>>>(x, xr, Wf, Wrf, y, part, ptok);
  final_loss<<<1, 256, 0, stream>>>(ptok, y, out);
}